// Round 1
// baseline (1006.224 us; speedup 1.0000x reference)
//
#include <hip/hip_runtime.h>
#include <hip/hip_bf16.h>
#include <stdint.h>

typedef __attribute__((ext_vector_type(8))) short s16x8;
typedef __attribute__((ext_vector_type(4))) float f32x4;
typedef __attribute__((ext_vector_type(4))) unsigned short u16x4;
typedef __hip_bfloat16 bf16;

#define MFMA16(a, b, c) __builtin_amdgcn_mfma_f32_16x16x32_bf16((a), (b), (c), 0, 0, 0)

static __device__ __forceinline__ unsigned short bfbits(float f) {
    bf16 h = __float2bfloat16(f);
    unsigned short u;
    __builtin_memcpy(&u, &h, 2);
    return u;
}

// ---------------------------------------------------------------------------
// Weight prep: cast to bf16 and transpose to [N][K] (NT layout for all GEMMs)
// wt layout (elements): WqT@0, WkT@147456, WvT@294912, WoT@442368,
//                       W1T@589824 (1536x384), W2T@1179648 (384x1536)
// ---------------------------------------------------------------------------
__global__ void k_prep_weights(const float* __restrict__ Wq, const float* __restrict__ Wk,
                               const float* __restrict__ Wv, const float* __restrict__ Wo,
                               const float* __restrict__ W1, const float* __restrict__ W2,
                               bf16* __restrict__ wt)
{
    int idx = blockIdx.x * 256 + threadIdx.x;
    if (idx >= 1769472) return;
    float v;
    if (idx < 589824) {
        int which = idx / 147456, rem = idx % 147456;
        int n = rem / 384, kk = rem % 384;
        const float* src = (which == 0) ? Wq : (which == 1) ? Wk : (which == 2) ? Wv : Wo;
        v = src[kk * 384 + n];
    } else if (idx < 1179648) {
        int rem = idx - 589824;
        int n = rem / 384, kk = rem % 384;
        v = W1[kk * 1536 + n];
    } else {
        int rem = idx - 1179648;
        int n = rem / 1536, kk = rem % 1536;
        v = W2[kk * 384 + n];
    }
    wt[idx] = __float2bfloat16(v);
}

// ---------------------------------------------------------------------------
// LayerNorm: one wave per row of 384 f32 -> bf16. Block = 4 waves = 4 rows.
// ---------------------------------------------------------------------------
__global__ __launch_bounds__(256) void k_layernorm(const float* __restrict__ x,
                                                   const float* __restrict__ g,
                                                   const float* __restrict__ b,
                                                   bf16* __restrict__ h)
{
    int row = blockIdx.x * 4 + (threadIdx.x >> 6);
    int lane = threadIdx.x & 63;
    const float* xr = x + (size_t)row * 384;
    float v[6];
    float s = 0.f, s2 = 0.f;
#pragma unroll
    for (int j = 0; j < 6; ++j) {
        float t = xr[lane + 64 * j];
        v[j] = t; s += t; s2 += t * t;
    }
#pragma unroll
    for (int d = 32; d >= 1; d >>= 1) {
        s += __shfl_xor(s, d);
        s2 += __shfl_xor(s2, d);
    }
    float mu = s * (1.f / 384.f);
    float var = s2 * (1.f / 384.f) - mu * mu;
    float rs = rsqrtf(var + 1e-5f);
    bf16* hr = h + (size_t)row * 384;
#pragma unroll
    for (int j = 0; j < 6; ++j) {
        int c = lane + 64 * j;
        hr[c] = __float2bfloat16((v[j] - mu) * rs * g[c] + b[c]);
    }
}

// ---------------------------------------------------------------------------
// GEMM-NT: C[M,N] = A[M,K] @ Bt[N,K]^T (+bias, epilogue variants)
// 128x128 tile, BK=64, 256 threads (4 waves, 2x2 wave grid, 64x64 per wave).
// Reg-staged LDS with XOR swizzle (T2-style), next-tile register prefetch.
// EPI: 0 = bias -> bf16
//      1 = bias + exact GELU -> bf16
//      2 = bias + residual(f32) -> f32
//      3 = bias -> bf16, output transposed per batch of 2048 rows (makes vT)
// ---------------------------------------------------------------------------
template <int EPI>
__global__ __launch_bounds__(256, 2)
void k_gemm_nt(const bf16* __restrict__ A, const bf16* __restrict__ Bt,
               const float* __restrict__ bias, const float* __restrict__ res,
               void* __restrict__ outp, int M, int N, int K)
{
    __shared__ char As[16384];
    __shared__ char Bs[16384];
    const int tid = threadIdx.x;
    const int w = tid >> 6, l = tid & 63;
    const int l15 = l & 15, lg = l >> 4;
    const int brow = blockIdx.y * 128, bcol = blockIdx.x * 128;
    const int wr = (w >> 1) * 64, wc = (w & 1) * 64;

    f32x4 acc[4][4];
#pragma unroll
    for (int i = 0; i < 4; ++i)
#pragma unroll
        for (int j = 0; j < 4; ++j) acc[i][j] = (f32x4){0.f, 0.f, 0.f, 0.f};

    // staging: 4 chunks of 16B per thread for each of A, B
    const bf16* gA[4];
    const bf16* gB[4];
    int offw[4];
#pragma unroll
    for (int j = 0; j < 4; ++j) {
        int idx = j * 256 + tid;
        int row = idx >> 3, c8 = (idx & 7) << 3;
        gA[j] = A + (size_t)(brow + row) * K + c8;
        gB[j] = Bt + (size_t)(bcol + row) * K + c8;
        offw[j] = ((row << 7) | (c8 << 1)) ^ ((row & 7) << 4);
    }

    s16x8 ar[4], br[4];
#pragma unroll
    for (int j = 0; j < 4; ++j) {
        ar[j] = *reinterpret_cast<const s16x8*>(gA[j]);
        br[j] = *reinterpret_cast<const s16x8*>(gB[j]);
    }

    const int nk = K >> 6;
    for (int kt = 0; kt < nk; ++kt) {
        __syncthreads();
#pragma unroll
        for (int j = 0; j < 4; ++j) {
            *reinterpret_cast<s16x8*>(As + offw[j]) = ar[j];
            *reinterpret_cast<s16x8*>(Bs + offw[j]) = br[j];
        }
        __syncthreads();
        if (kt + 1 < nk) {
            int k0 = (kt + 1) << 6;
#pragma unroll
            for (int j = 0; j < 4; ++j) {
                ar[j] = *reinterpret_cast<const s16x8*>(gA[j] + k0);
                br[j] = *reinterpret_cast<const s16x8*>(gB[j] + k0);
            }
        }
#pragma unroll
        for (int kc = 0; kc < 2; ++kc) {
            int cb = (kc * 32 + lg * 8) << 1;  // byte col within 128B row
            s16x8 af[4], bfr[4];
#pragma unroll
            for (int i = 0; i < 4; ++i) {
                int rowA = wr + i * 16 + l15;
                af[i] = *reinterpret_cast<const s16x8*>(As + ((rowA << 7) | (cb ^ ((rowA & 7) << 4))));
                int rowB = wc + i * 16 + l15;
                bfr[i] = *reinterpret_cast<const s16x8*>(Bs + ((rowB << 7) | (cb ^ ((rowB & 7) << 4))));
            }
#pragma unroll
            for (int i = 0; i < 4; ++i)
#pragma unroll
                for (int j = 0; j < 4; ++j)
                    acc[i][j] = MFMA16(af[i], bfr[j], acc[i][j]);
        }
    }

    // epilogue: C/D layout col = lane&15, row = (lane>>4)*4 + r
#pragma unroll
    for (int i = 0; i < 4; ++i) {
#pragma unroll
        for (int j = 0; j < 4; ++j) {
            int col = bcol + wc + j * 16 + l15;
            float bi = bias[col];
            int row0 = brow + wr + i * 16 + lg * 4;
            if constexpr (EPI == 3) {
                u16x4 pk;
#pragma unroll
                for (int r = 0; r < 4; ++r) pk[r] = bfbits(acc[i][j][r] + bi);
                int batch = row0 >> 11, rloc = row0 & 2047;
                bf16* dst = (bf16*)outp + (size_t)batch * 786432 + (size_t)col * 2048 + rloc;
                *reinterpret_cast<u16x4*>(dst) = pk;
            } else {
#pragma unroll
                for (int r = 0; r < 4; ++r) {
                    int row = row0 + r;
                    float val = acc[i][j][r] + bi;
                    if constexpr (EPI == 0) {
                        ((bf16*)outp)[(size_t)row * N + col] = __float2bfloat16(val);
                    } else if constexpr (EPI == 1) {
                        float ge = 0.5f * val * (1.f + erff(val * 0.70710678118654752f));
                        ((bf16*)outp)[(size_t)row * N + col] = __float2bfloat16(ge);
                    } else {  // EPI == 2
                        ((float*)outp)[(size_t)row * N + col] = res[(size_t)row * N + col] + val;
                    }
                }
            }
        }
    }
}

// ---------------------------------------------------------------------------
// Flash attention: B=16, S=2048, d=384 (single head).
// Block = 4 waves, QBLK=32 rows, KBLK=64, 32 iterations.
// Wave w: QK for S cols [16w,16w+16), softmax rows [8w,8w+8), PV cols [96w,96w+96).
// Q in regs; K streamed from global (L2); V consumed from global vT (L2).
// XCD pinning: batch = (bid&7) + 8*(bid>>9) -> one batch per XCD phase.
// ---------------------------------------------------------------------------
__global__ __launch_bounds__(256, 2)
void k_flash_attn(const bf16* __restrict__ q, const bf16* __restrict__ k,
                  const bf16* __restrict__ vT, bf16* __restrict__ av)
{
    const int bid = blockIdx.x;
    const int batch = (bid & 7) + ((bid >> 9) << 3);
    const int qblk = (bid >> 3) & 63;
    const int q0 = qblk * 32;
    const bf16* qb = q + (size_t)batch * (2048 * 384);
    const bf16* kb = k + (size_t)batch * (2048 * 384);
    const bf16* vb = vT + (size_t)batch * (384 * 2048);
    bf16* avb = av + (size_t)batch * (2048 * 384);
    const int tid = threadIdx.x, w = tid >> 6, l = tid & 63;
    const int l15 = l & 15, lg = l >> 4;

    __shared__ float S_lds[32 * 68];
    __shared__ unsigned short P_lds[32 * 80];
    __shared__ float m_lds[32], l_lds[32], f_lds[32];
    if (tid < 32) { m_lds[tid] = -1e30f; l_lds[tid] = 0.f; }

    // Q fragments resident in registers: [m in 0..1][kc in 0..11]
    s16x8 qf[2][12];
#pragma unroll
    for (int m = 0; m < 2; ++m)
#pragma unroll
        for (int kc = 0; kc < 12; ++kc)
            qf[m][kc] = *reinterpret_cast<const s16x8*>(
                qb + (size_t)(q0 + m * 16 + l15) * 384 + kc * 32 + lg * 8);

    f32x4 o[2][6];
#pragma unroll
    for (int m = 0; m < 2; ++m)
#pragma unroll
        for (int n = 0; n < 6; ++n) o[m][n] = (f32x4){0.f, 0.f, 0.f, 0.f};

    const float kScale = 1.4426950408889634f * 0.05103103630798288f;  // log2(e)/sqrt(384)

    for (int kt = 0; kt < 32; ++kt) {
        // ---- phase A: S[32, 16w..16w+16) = Q @ K^T ----
        f32x4 sA = (f32x4){0.f, 0.f, 0.f, 0.f};
        f32x4 sB = (f32x4){0.f, 0.f, 0.f, 0.f};
        const bf16* kp = kb + (size_t)(kt * 64 + w * 16 + l15) * 384 + lg * 8;
#pragma unroll
        for (int kc = 0; kc < 12; ++kc) {
            s16x8 kf = *reinterpret_cast<const s16x8*>(kp + kc * 32);
            sA = MFMA16(qf[0][kc], kf, sA);
            sB = MFMA16(qf[1][kc], kf, sB);
        }
        int scol = w * 16 + l15;
#pragma unroll
        for (int r = 0; r < 4; ++r) {
            S_lds[(lg * 4 + r) * 68 + scol] = sA[r];
            S_lds[(16 + lg * 4 + r) * 68 + scol] = sB[r];
        }
        __syncthreads();
        // ---- phase B: online softmax, rows 8w..8w+8 ----
#pragma unroll
        for (int rr = 0; rr < 8; ++rr) {
            int r = w * 8 + rr;
            float sv = S_lds[r * 68 + l] * kScale;
            float mx = sv;
#pragma unroll
            for (int d = 32; d >= 1; d >>= 1) mx = fmaxf(mx, __shfl_xor(mx, d));
            float mo = m_lds[r];
            float mn = fmaxf(mo, mx);
            float p = exp2f(sv - mn);
            float ps = p;
#pragma unroll
            for (int d = 32; d >= 1; d >>= 1) ps += __shfl_xor(ps, d);
            if (l == 0) {
                float f = exp2f(mo - mn);
                l_lds[r] = l_lds[r] * f + ps;
                m_lds[r] = mn;
                f_lds[r] = f;
            }
            P_lds[r * 80 + l] = bfbits(p);
        }
        __syncthreads();
        // ---- phase C: O rescale + O += P @ V ----
        float fr[2][4];
#pragma unroll
        for (int m = 0; m < 2; ++m)
#pragma unroll
            for (int r = 0; r < 4; ++r) fr[m][r] = f_lds[m * 16 + lg * 4 + r];
#pragma unroll
        for (int m = 0; m < 2; ++m)
#pragma unroll
            for (int n = 0; n < 6; ++n)
#pragma unroll
                for (int r = 0; r < 4; ++r) o[m][n][r] *= fr[m][r];
        s16x8 pf[2][2];
#pragma unroll
        for (int m = 0; m < 2; ++m)
#pragma unroll
            for (int kc2 = 0; kc2 < 2; ++kc2)
                pf[m][kc2] = *reinterpret_cast<const s16x8*>(
                    P_lds + (m * 16 + l15) * 80 + kc2 * 32 + lg * 8);
        const bf16* vp = vb + (size_t)(w * 96 + l15) * 2048 + kt * 64 + lg * 8;
#pragma unroll
        for (int n = 0; n < 6; ++n) {
            const bf16* vpn = vp + n * 16 * 2048;
#pragma unroll
            for (int kc2 = 0; kc2 < 2; ++kc2) {
                s16x8 vf = *reinterpret_cast<const s16x8*>(vpn + kc2 * 32);
                o[0][n] = MFMA16(pf[0][kc2], vf, o[0][n]);
                o[1][n] = MFMA16(pf[1][kc2], vf, o[1][n]);
            }
        }
        // no barrier needed: next phase A only writes S_lds (not read here);
        // P_lds/f_lds rewrites are fenced by the A->B barrier of the next iter.
    }

    // ---- epilogue: av = O / l ----
    float li[2][4];
#pragma unroll
    for (int m = 0; m < 2; ++m)
#pragma unroll
        for (int r = 0; r < 4; ++r) li[m][r] = 1.f / l_lds[m * 16 + lg * 4 + r];
#pragma unroll
    for (int m = 0; m < 2; ++m)
#pragma unroll
        for (int n = 0; n < 6; ++n)
#pragma unroll
            for (int r = 0; r < 4; ++r)
                avb[(size_t)(q0 + m * 16 + lg * 4 + r) * 384 + w * 96 + n * 16 + l15] =
                    __float2bfloat16(o[m][n][r] * li[m][r]);
}

// ---------------------------------------------------------------------------
// Launch: 10 kernels.
// ws layout (bytes):
//   wt   @ 0          (3,538,944)
//   q    @ 3,538,944  (25,165,824)
//   k    @ 28,704,768 (25,165,824)
//   vT   @ 53,870,592 (25,165,824)
//   av   @ 79,036,416 (25,165,824)   [= h1 early]
//   h2   @ 104,202,240(25,165,824)   [= h3 late]
//   hh aliases q..av (100,663,296)   total = 129,368,064
// ---------------------------------------------------------------------------
extern "C" void kernel_launch(void* const* d_in, const int* in_sizes, int n_in,
                              void* d_out, int out_size, void* d_ws, size_t ws_size,
                              hipStream_t stream)
{
    const float* x1 = (const float*)d_in[0];
    const float* x2 = (const float*)d_in[1];
    const float* ln1_g = (const float*)d_in[2];
    const float* ln1_b = (const float*)d_in[3];
    const float* ln2_g = (const float*)d_in[4];
    const float* ln2_b = (const float*)d_in[5];
    const float* Wq = (const float*)d_in[6];
    const float* bq = (const float*)d_in[7];
    const float* Wk = (const float*)d_in[8];
    const float* bk = (const float*)d_in[9];
    const float* Wv = (const float*)d_in[10];
    const float* bv = (const float*)d_in[11];
    const float* Wo = (const float*)d_in[12];
    const float* bo = (const float*)d_in[13];
    const float* ln3_g = (const float*)d_in[14];
    const float* ln3_b = (const float*)d_in[15];
    const float* W1 = (const float*)d_in[16];
    const float* b1 = (const float*)d_in[17];
    const float* W2 = (const float*)d_in[18];
    const float* b2 = (const float*)d_in[19];
    float* out = (float*)d_out;

    char* ws = (char*)d_ws;
    bf16* wt = (bf16*)(ws);
    bf16* qB = (bf16*)(ws + 3538944);
    bf16* kB = (bf16*)(ws + 28704768);
    bf16* vTB = (bf16*)(ws + 53870592);
    bf16* avB = (bf16*)(ws + 79036416);
    bf16* h2B = (bf16*)(ws + 104202240);
    bf16* h1B = avB;   // h1 aliases av (dead before attention output)
    bf16* h3B = h2B;   // h3 aliases h2 (dead after k/v projections)
    bf16* hhB = qB;    // hh aliases q|k|vT|av (all dead after Wo projection)

    const bf16* WqT = wt;
    const bf16* WkT = wt + 147456;
    const bf16* WvT = wt + 294912;
    const bf16* WoT = wt + 442368;
    const bf16* W1T = wt + 589824;
    const bf16* W2T = wt + 1179648;

    k_prep_weights<<<6912, 256, 0, stream>>>(Wq, Wk, Wv, Wo, W1, W2, wt);
    k_layernorm<<<8192, 256, 0, stream>>>(x1, ln1_g, ln1_b, h1B);
    k_layernorm<<<8192, 256, 0, stream>>>(x2, ln2_g, ln2_b, h2B);

    dim3 g384(3, 256), g1536(12, 256);
    k_gemm_nt<0><<<g384, 256, 0, stream>>>(h1B, WqT, bq, nullptr, qB, 32768, 384, 384);
    k_gemm_nt<0><<<g384, 256, 0, stream>>>(h2B, WkT, bk, nullptr, kB, 32768, 384, 384);
    k_gemm_nt<3><<<g384, 256, 0, stream>>>(h2B, WvT, bv, nullptr, vTB, 32768, 384, 384);

    k_flash_attn<<<1024, 256, 0, stream>>>(qB, kB, vTB, avB);

    k_gemm_nt<2><<<g384, 256, 0, stream>>>(avB, WoT, bo, x1, out, 32768, 384, 384);
    k_layernorm<<<8192, 256, 0, stream>>>(out, ln3_g, ln3_b, h3B);
    k_gemm_nt<1><<<g1536, 256, 0, stream>>>(h3B, W1T, b1, nullptr, hhB, 32768, 1536, 384);
    k_gemm_nt<2><<<g384, 256, 0, stream>>>(hhB, W2T, b2, out, out, 32768, 384, 1536);
}

// Round 2
// 829.110 us; speedup vs baseline: 1.2136x; 1.2136x over previous
//
#include <hip/hip_runtime.h>
#include <hip/hip_bf16.h>
#include <stdint.h>

typedef __attribute__((ext_vector_type(8))) short s16x8;
typedef __attribute__((ext_vector_type(4))) float f32x4;
typedef __attribute__((ext_vector_type(4))) unsigned short u16x4;
typedef __hip_bfloat16 bf16;

#define MFMA16(a, b, c) __builtin_amdgcn_mfma_f32_16x16x32_bf16((a), (b), (c), 0, 0, 0)

static __device__ __forceinline__ unsigned short bfbits(float f) {
    bf16 h = __float2bfloat16(f);
    unsigned short u;
    __builtin_memcpy(&u, &h, 2);
    return u;
}

// ---------------------------------------------------------------------------
// Weight prep: cast to bf16 and transpose to [N][K] (NT layout for all GEMMs)
// ---------------------------------------------------------------------------
__global__ void k_prep_weights(const float* __restrict__ Wq, const float* __restrict__ Wk,
                               const float* __restrict__ Wv, const float* __restrict__ Wo,
                               const float* __restrict__ W1, const float* __restrict__ W2,
                               bf16* __restrict__ wt)
{
    int idx = blockIdx.x * 256 + threadIdx.x;
    if (idx >= 1769472) return;
    float v;
    if (idx < 589824) {
        int which = idx / 147456, rem = idx % 147456;
        int n = rem / 384, kk = rem % 384;
        const float* src = (which == 0) ? Wq : (which == 1) ? Wk : (which == 2) ? Wv : Wo;
        v = src[kk * 384 + n];
    } else if (idx < 1179648) {
        int rem = idx - 589824;
        int n = rem / 384, kk = rem % 384;
        v = W1[kk * 1536 + n];
    } else {
        int rem = idx - 1179648;
        int n = rem / 1536, kk = rem % 1536;
        v = W2[kk * 384 + n];
    }
    wt[idx] = __float2bfloat16(v);
}

// ---------------------------------------------------------------------------
// LayerNorm: one wave per row of 384 f32 -> bf16. Block = 4 waves = 4 rows.
// ---------------------------------------------------------------------------
__global__ __launch_bounds__(256) void k_layernorm(const float* __restrict__ x,
                                                   const float* __restrict__ g,
                                                   const float* __restrict__ b,
                                                   bf16* __restrict__ h)
{
    int row = blockIdx.x * 4 + (threadIdx.x >> 6);
    int lane = threadIdx.x & 63;
    const float* xr = x + (size_t)row * 384;
    float v[6];
    float s = 0.f, s2 = 0.f;
#pragma unroll
    for (int j = 0; j < 6; ++j) {
        float t = xr[lane + 64 * j];
        v[j] = t; s += t; s2 += t * t;
    }
#pragma unroll
    for (int d = 32; d >= 1; d >>= 1) {
        s += __shfl_xor(s, d);
        s2 += __shfl_xor(s2, d);
    }
    float mu = s * (1.f / 384.f);
    float var = s2 * (1.f / 384.f) - mu * mu;
    float rs = rsqrtf(var + 1e-5f);
    bf16* hr = h + (size_t)row * 384;
#pragma unroll
    for (int j = 0; j < 6; ++j) {
        int c = lane + 64 * j;
        hr[c] = __float2bfloat16((v[j] - mu) * rs * g[c] + b[c]);
    }
}

// ---------------------------------------------------------------------------
// GEMM-NT: C[M,N] = A[M,K] @ Bt[N,K]^T (+bias, epilogue variants)
// 128x128 tile, BK=64, 256 threads (4 waves, 2x2 wave grid, 64x64 per wave).
// EPI: 0 = bias -> bf16
//      1 = bias + exact GELU -> bf16
//      2 = bias + residual(f32) -> f32
//      3 = bias -> bf16, output transposed per batch of 2048 rows (makes vT)
// ---------------------------------------------------------------------------
template <int EPI>
__global__ __launch_bounds__(256, 2)
void k_gemm_nt(const bf16* __restrict__ A, const bf16* __restrict__ Bt,
               const float* __restrict__ bias, const float* __restrict__ res,
               void* __restrict__ outp, int M, int N, int K)
{
    __shared__ char As[16384];
    __shared__ char Bs[16384];
    const int tid = threadIdx.x;
    const int w = tid >> 6, l = tid & 63;
    const int l15 = l & 15, lg = l >> 4;
    const int brow = blockIdx.y * 128, bcol = blockIdx.x * 128;
    const int wr = (w >> 1) * 64, wc = (w & 1) * 64;

    f32x4 acc[4][4];
#pragma unroll
    for (int i = 0; i < 4; ++i)
#pragma unroll
        for (int j = 0; j < 4; ++j) acc[i][j] = (f32x4){0.f, 0.f, 0.f, 0.f};

    const bf16* gA[4];
    const bf16* gB[4];
    int offw[4];
#pragma unroll
    for (int j = 0; j < 4; ++j) {
        int idx = j * 256 + tid;
        int row = idx >> 3, c8 = (idx & 7) << 3;
        gA[j] = A + (size_t)(brow + row) * K + c8;
        gB[j] = Bt + (size_t)(bcol + row) * K + c8;
        offw[j] = ((row << 7) | (c8 << 1)) ^ ((row & 7) << 4);
    }

    s16x8 ar[4], br[4];
#pragma unroll
    for (int j = 0; j < 4; ++j) {
        ar[j] = *reinterpret_cast<const s16x8*>(gA[j]);
        br[j] = *reinterpret_cast<const s16x8*>(gB[j]);
    }

    const int nk = K >> 6;
    for (int kt = 0; kt < nk; ++kt) {
        __syncthreads();
#pragma unroll
        for (int j = 0; j < 4; ++j) {
            *reinterpret_cast<s16x8*>(As + offw[j]) = ar[j];
            *reinterpret_cast<s16x8*>(Bs + offw[j]) = br[j];
        }
        __syncthreads();
        if (kt + 1 < nk) {
            int k0 = (kt + 1) << 6;
#pragma unroll
            for (int j = 0; j < 4; ++j) {
                ar[j] = *reinterpret_cast<const s16x8*>(gA[j] + k0);
                br[j] = *reinterpret_cast<const s16x8*>(gB[j] + k0);
            }
        }
#pragma unroll
        for (int kc = 0; kc < 2; ++kc) {
            int cb = (kc * 32 + lg * 8) << 1;
            s16x8 af[4], bfr[4];
#pragma unroll
            for (int i = 0; i < 4; ++i) {
                int rowA = wr + i * 16 + l15;
                af[i] = *reinterpret_cast<const s16x8*>(As + ((rowA << 7) | (cb ^ ((rowA & 7) << 4))));
                int rowB = wc + i * 16 + l15;
                bfr[i] = *reinterpret_cast<const s16x8*>(Bs + ((rowB << 7) | (cb ^ ((rowB & 7) << 4))));
            }
#pragma unroll
            for (int i = 0; i < 4; ++i)
#pragma unroll
                for (int j = 0; j < 4; ++j)
                    acc[i][j] = MFMA16(af[i], bfr[j], acc[i][j]);
        }
    }

#pragma unroll
    for (int i = 0; i < 4; ++i) {
#pragma unroll
        for (int j = 0; j < 4; ++j) {
            int col = bcol + wc + j * 16 + l15;
            float bi = bias[col];
            int row0 = brow + wr + i * 16 + lg * 4;
            if constexpr (EPI == 3) {
                u16x4 pk;
#pragma unroll
                for (int r = 0; r < 4; ++r) pk[r] = bfbits(acc[i][j][r] + bi);
                int batch = row0 >> 11, rloc = row0 & 2047;
                bf16* dst = (bf16*)outp + (size_t)batch * 786432 + (size_t)col * 2048 + rloc;
                *reinterpret_cast<u16x4*>(dst) = pk;
            } else {
#pragma unroll
                for (int r = 0; r < 4; ++r) {
                    int row = row0 + r;
                    float val = acc[i][j][r] + bi;
                    if constexpr (EPI == 0) {
                        ((bf16*)outp)[(size_t)row * N + col] = __float2bfloat16(val);
                    } else if constexpr (EPI == 1) {
                        float ge = 0.5f * val * (1.f + erff(val * 0.70710678118654752f));
                        ((bf16*)outp)[(size_t)row * N + col] = __float2bfloat16(ge);
                    } else {
                        ((float*)outp)[(size_t)row * N + col] = res[(size_t)row * N + col] + val;
                    }
                }
            }
        }
    }
}

// ---------------------------------------------------------------------------
// Flash attention, swapped-QK^T fragment-parallel softmax.
// B=16, S=2048, d=384. Block = 4 waves, QBLK=32 rows, KBLK=64, 32 iterations.
// Wave w computes S^T[16 k-cols (w*16..), 32 q] via mfma(K,Q): each lane holds
// S for q-row = lane&15 (+16m), k = w*16 + (lane>>4)*4 + r  ->  row reductions
// are 3 VALU ops + 2 shfl_xor. Cross-wave merge via [32][4] LDS partials.
// Running m/l kept in registers (redundant per lane). P transposed via LDS.
// ---------------------------------------------------------------------------
__global__ __launch_bounds__(256, 2)
void k_flash_attn(const bf16* __restrict__ q, const bf16* __restrict__ k,
                  const bf16* __restrict__ vT, bf16* __restrict__ av)
{
    const int bid = blockIdx.x;
    const int batch = (bid & 7) + ((bid >> 9) << 3);
    const int qblk = (bid >> 3) & 63;
    const int q0 = qblk * 32;
    const bf16* qb = q + (size_t)batch * (2048 * 384);
    const bf16* kb = k + (size_t)batch * (2048 * 384);
    const bf16* vb = vT + (size_t)batch * (384 * 2048);
    bf16* avb = av + (size_t)batch * (2048 * 384);
    const int tid = threadIdx.x, w = tid >> 6, l = tid & 63;
    const int l15 = l & 15, lg = l >> 4;

    __shared__ __align__(16) float pm_lds[32][4];   // per-wave partial max
    __shared__ __align__(16) float ps_lds[32][4];   // per-wave partial sum
    __shared__ __align__(16) float f_lds[32];       // rescale factor per q-row
    __shared__ __align__(16) unsigned short P_lds[32 * 72];

    // Q fragments resident in registers (B-operand layout for swapped QK)
    s16x8 qf[2][12];
#pragma unroll
    for (int m = 0; m < 2; ++m)
#pragma unroll
        for (int kc = 0; kc < 12; ++kc)
            qf[m][kc] = *reinterpret_cast<const s16x8*>(
                qb + (size_t)(q0 + m * 16 + l15) * 384 + kc * 32 + lg * 8);

    f32x4 o[2][6];
#pragma unroll
    for (int m = 0; m < 2; ++m)
#pragma unroll
        for (int n = 0; n < 6; ++n) o[m][n] = (f32x4){0.f, 0.f, 0.f, 0.f};

    float m_run[2] = {-1e30f, -1e30f};
    float l_run[2] = {0.f, 0.f};

    const float kScale = 1.4426950408889634f * 0.05103103630798288f;  // log2(e)/sqrt(384)

    for (int kt = 0; kt < 32; ++kt) {
        // ---- QK^T (swapped): st[m] = S^T[k = w*16 + lg*4 + r][q = m*16 + l15]
        f32x4 st0 = (f32x4){0.f, 0.f, 0.f, 0.f};
        f32x4 st1 = (f32x4){0.f, 0.f, 0.f, 0.f};
        const bf16* kp = kb + (size_t)(kt * 64 + w * 16 + l15) * 384 + lg * 8;
#pragma unroll
        for (int kc = 0; kc < 12; ++kc) {
            s16x8 kf = *reinterpret_cast<const s16x8*>(kp + kc * 32);
            st0 = MFMA16(kf, qf[0][kc], st0);
            st1 = MFMA16(kf, qf[1][kc], st1);
        }
        // ---- per-wave partial max over the 16 k this wave owns (scaled domain)
        float pmax[2];
        pmax[0] = fmaxf(fmaxf(st0[0], st0[1]), fmaxf(st0[2], st0[3])) * kScale;
        pmax[1] = fmaxf(fmaxf(st1[0], st1[1]), fmaxf(st1[2], st1[3])) * kScale;
#pragma unroll
        for (int m = 0; m < 2; ++m) {
            pmax[m] = fmaxf(pmax[m], __shfl_xor(pmax[m], 16));
            pmax[m] = fmaxf(pmax[m], __shfl_xor(pmax[m], 32));
        }
        if (lg == 0) {
            pm_lds[l15][w] = pmax[0];
            pm_lds[16 + l15][w] = pmax[1];
        }
        __syncthreads();
        // ---- global max merge (every lane, redundantly, for q = m*16 + l15)
        float mn[2], f[2];
#pragma unroll
        for (int m = 0; m < 2; ++m) {
            f32x4 pm4 = *reinterpret_cast<const f32x4*>(&pm_lds[m * 16 + l15][0]);
            float mx = fmaxf(fmaxf(pm4[0], pm4[1]), fmaxf(pm4[2], pm4[3]));
            mn[m] = fmaxf(m_run[m], mx);
            f[m] = exp2f(m_run[m] - mn[m]);
            m_run[m] = mn[m];
        }
        if (w == 0 && lg == 0) {
            f_lds[l15] = f[0];
            f_lds[16 + l15] = f[1];
        }
        // ---- P = exp2(S*c - mn), partial sums, P -> LDS (bf16)
#pragma unroll
        for (int m = 0; m < 2; ++m) {
            const f32x4 stv = m ? st1 : st0;
            float p0 = exp2f(fmaf(stv[0], kScale, -mn[m]));
            float p1 = exp2f(fmaf(stv[1], kScale, -mn[m]));
            float p2 = exp2f(fmaf(stv[2], kScale, -mn[m]));
            float p3 = exp2f(fmaf(stv[3], kScale, -mn[m]));
            float ps = (p0 + p1) + (p2 + p3);
            ps += __shfl_xor(ps, 16);
            ps += __shfl_xor(ps, 32);
            if (lg == 0) ps_lds[m * 16 + l15][w] = ps;
            u16x4 pk;
            pk[0] = bfbits(p0); pk[1] = bfbits(p1); pk[2] = bfbits(p2); pk[3] = bfbits(p3);
            *reinterpret_cast<u16x4*>(&P_lds[(m * 16 + l15) * 72 + w * 16 + lg * 4]) = pk;
        }
        __syncthreads();
        // ---- merge l, rescale O
        f32x4 frv[2];
#pragma unroll
        for (int m = 0; m < 2; ++m) {
            f32x4 s4 = *reinterpret_cast<const f32x4*>(&ps_lds[m * 16 + l15][0]);
            l_run[m] = l_run[m] * f[m] + ((s4[0] + s4[1]) + (s4[2] + s4[3]));
            frv[m] = *reinterpret_cast<const f32x4*>(&f_lds[m * 16 + lg * 4]);
        }
#pragma unroll
        for (int m = 0; m < 2; ++m)
#pragma unroll
            for (int n = 0; n < 6; ++n)
#pragma unroll
                for (int r = 0; r < 4; ++r) o[m][n][r] *= frv[m][r];
        // ---- P fragments (A-operand layout) + PV
        s16x8 pf[2][2];
#pragma unroll
        for (int m = 0; m < 2; ++m)
#pragma unroll
            for (int kc2 = 0; kc2 < 2; ++kc2)
                pf[m][kc2] = *reinterpret_cast<const s16x8*>(
                    &P_lds[(m * 16 + l15) * 72 + kc2 * 32 + lg * 8]);
        const bf16* vp = vb + (size_t)(w * 96 + l15) * 2048 + kt * 64 + lg * 8;
#pragma unroll
        for (int n = 0; n < 6; ++n) {
            const bf16* vpn = vp + n * 16 * 2048;
#pragma unroll
            for (int kc2 = 0; kc2 < 2; ++kc2) {
                s16x8 vf = *reinterpret_cast<const s16x8*>(vpn + kc2 * 32);
                o[0][n] = MFMA16(pf[0][kc2], vf, o[0][n]);
                o[1][n] = MFMA16(pf[1][kc2], vf, o[1][n]);
            }
        }
        // no extra barrier: next-iter LDS writes are fenced by b1/b2 (see notes)
    }

    // ---- epilogue: av = O / l   (transpose 1/l through LDS, reuse f_lds)
    __syncthreads();
    if (w == 0 && lg == 0) {
        f_lds[l15] = 1.f / l_run[0];
        f_lds[16 + l15] = 1.f / l_run[1];
    }
    __syncthreads();
    f32x4 lv[2];
#pragma unroll
    for (int m = 0; m < 2; ++m)
        lv[m] = *reinterpret_cast<const f32x4*>(&f_lds[m * 16 + lg * 4]);
#pragma unroll
    for (int m = 0; m < 2; ++m)
#pragma unroll
        for (int n = 0; n < 6; ++n)
#pragma unroll
            for (int r = 0; r < 4; ++r)
                avb[(size_t)(q0 + m * 16 + lg * 4 + r) * 384 + w * 96 + n * 16 + l15] =
                    __float2bfloat16(o[m][n][r] * lv[m][r]);
}

// ---------------------------------------------------------------------------
// Launch: 10 kernels. ws layout as before (129.4 MB).
// ---------------------------------------------------------------------------
extern "C" void kernel_launch(void* const* d_in, const int* in_sizes, int n_in,
                              void* d_out, int out_size, void* d_ws, size_t ws_size,
                              hipStream_t stream)
{
    const float* x1 = (const float*)d_in[0];
    const float* x2 = (const float*)d_in[1];
    const float* ln1_g = (const float*)d_in[2];
    const float* ln1_b = (const float*)d_in[3];
    const float* ln2_g = (const float*)d_in[4];
    const float* ln2_b = (const float*)d_in[5];
    const float* Wq = (const float*)d_in[6];
    const float* bq = (const float*)d_in[7];
    const float* Wk = (const float*)d_in[8];
    const float* bk = (const float*)d_in[9];
    const float* Wv = (const float*)d_in[10];
    const float* bv = (const float*)d_in[11];
    const float* Wo = (const float*)d_in[12];
    const float* bo = (const float*)d_in[13];
    const float* ln3_g = (const float*)d_in[14];
    const float* ln3_b = (const float*)d_in[15];
    const float* W1 = (const float*)d_in[16];
    const float* b1 = (const float*)d_in[17];
    const float* W2 = (const float*)d_in[18];
    const float* b2 = (const float*)d_in[19];
    float* out = (float*)d_out;

    char* ws = (char*)d_ws;
    bf16* wt = (bf16*)(ws);
    bf16* qB = (bf16*)(ws + 3538944);
    bf16* kB = (bf16*)(ws + 28704768);
    bf16* vTB = (bf16*)(ws + 53870592);
    bf16* avB = (bf16*)(ws + 79036416);
    bf16* h2B = (bf16*)(ws + 104202240);
    bf16* h1B = avB;   // h1 aliases av (dead before attention output)
    bf16* h3B = h2B;   // h3 aliases h2 (dead after k/v projections)
    bf16* hhB = qB;    // hh aliases q|k|vT|av (all dead after Wo projection)

    const bf16* WqT = wt;
    const bf16* WkT = wt + 147456;
    const bf16* WvT = wt + 294912;
    const bf16* WoT = wt + 442368;
    const bf16* W1T = wt + 589824;
    const bf16* W2T = wt + 1179648;

    k_prep_weights<<<6912, 256, 0, stream>>>(Wq, Wk, Wv, Wo, W1, W2, wt);
    k_layernorm<<<8192, 256, 0, stream>>>(x1, ln1_g, ln1_b, h1B);
    k_layernorm<<<8192, 256, 0, stream>>>(x2, ln2_g, ln2_b, h2B);

    dim3 g384(3, 256), g1536(12, 256);
    k_gemm_nt<0><<<g384, 256, 0, stream>>>(h1B, WqT, bq, nullptr, qB, 32768, 384, 384);
    k_gemm_nt<0><<<g384, 256, 0, stream>>>(h2B, WkT, bk, nullptr, kB, 32768, 384, 384);
    k_gemm_nt<3><<<g384, 256, 0, stream>>>(h2B, WvT, bv, nullptr, vTB, 32768, 384, 384);

    k_flash_attn<<<1024, 256, 0, stream>>>(qB, kB, vTB, avB);

    k_gemm_nt<2><<<g384, 256, 0, stream>>>(avB, WoT, bo, x1, out, 32768, 384, 384);
    k_layernorm<<<8192, 256, 0, stream>>>(out, ln3_g, ln3_b, h3B);
    k_gemm_nt<1><<<g1536, 256, 0, stream>>>(h3B, W1T, b1, nullptr, hhB, 32768, 1536, 384);
    k_gemm_nt<2><<<g384, 256, 0, stream>>>(hhB, W2T, b2, out, out, 32768, 384, 1536);
}